// Round 3
// baseline (389.750 us; speedup 1.0000x reference)
//
#include <hip/hip_runtime.h>
#include <math.h>

#define EPS 1e-5f
#define NPK (4096 * 128)   // 524288 pixels

typedef __attribute__((ext_vector_type(8))) short bf16x8;   // 8 bf16 = 4 VGPRs
typedef __attribute__((ext_vector_type(4))) float f32x4;

__device__ __forceinline__ short f2bf(float f) {
    union { float f; unsigned u; } x; x.f = f;
    unsigned r = x.u + 0x7fffu + ((x.u >> 16) & 1u);   // round-to-nearest-even
    return (short)(r >> 16);
}

// ws layout (floats): A1[192] C1[64] C2[64] C3[128] | bf16: W2frag[4096] W3frag[8192]
// WNfrag holds BN-folded weights pre-swizzled into MFMA B-fragment per-lane order:
//   frag[((nt*2+ks)*64 + lane)*8 + j] = Wfold[o = nt*16 + (lane&15)][i = ks*32 + (lane>>4)*8 + j]
// so the kernel loads one bf16x8 per lane, consecutive lanes contiguous (L1-resident).
#define WS_A1 0
#define WS_C1 192
#define WS_C2 256
#define WS_C3 320
#define WS_BF 448

__global__ void prep_kernel(
    const float* __restrict__ W1, const float* __restrict__ b1,
    const float* __restrict__ g1, const float* __restrict__ be1,
    const float* __restrict__ m1, const float* __restrict__ v1,
    const float* __restrict__ W2, const float* __restrict__ b2,
    const float* __restrict__ g2, const float* __restrict__ be2,
    const float* __restrict__ m2, const float* __restrict__ v2,
    const float* __restrict__ W3, const float* __restrict__ b3,
    const float* __restrict__ g3, const float* __restrict__ be3,
    const float* __restrict__ m3, const float* __restrict__ v3,
    float* __restrict__ ws)
{
    const int t = threadIdx.x;
    if (t < 64) {
        float inv1 = g1[t] * rsqrtf(v1[t] + EPS);
        ws[WS_C1 + t] = b1[t] * inv1 + be1[t] - m1[t] * inv1;
        ws[WS_A1 + t * 3 + 0] = W1[t * 3 + 0] * inv1;
        ws[WS_A1 + t * 3 + 1] = W1[t * 3 + 1] * inv1;
        ws[WS_A1 + t * 3 + 2] = W1[t * 3 + 2] * inv1;
        float inv2 = g2[t] * rsqrtf(v2[t] + EPS);
        ws[WS_C2 + t] = b2[t] * inv2 + be2[t] - m2[t] * inv2;
    }
    if (t < 128) {
        float inv3 = g3[t] * rsqrtf(v3[t] + EPS);
        ws[WS_C3 + t] = b3[t] * inv3 + be3[t] - m3[t] * inv3;
    }
    short* W2f = (short*)(ws + WS_BF);
    short* W3f = W2f + 64 * 64;
    // W2frag: 4096 entries (4 n-tiles x 2 k-halves)
    for (int idx = t; idx < 64 * 64; idx += 256) {
        int j = idx & 7, lane = (idx >> 3) & 63, tile = idx >> 9;
        int nt = tile >> 1, ks = tile & 1;
        int o = nt * 16 + (lane & 15);
        int i = ks * 32 + (lane >> 4) * 8 + j;
        float inv = g2[o] * rsqrtf(v2[o] + EPS);
        W2f[idx] = f2bf(W2[o * 64 + i] * inv);
    }
    // W3frag: 8192 entries (8 n-tiles x 2 k-halves)
    for (int idx = t; idx < 128 * 64; idx += 256) {
        int j = idx & 7, lane = (idx >> 3) & 63, tile = idx >> 9;
        int nt = tile >> 1, ks = tile & 1;
        int o = nt * 16 + (lane & 15);
        int i = ks * 32 + (lane >> 4) * 8 + j;
        float inv = g3[o] * rsqrtf(v3[o] + EPS);
        W3f[idx] = f2bf(W3[o * 64 + i] * inv);
    }
}

// One block = 256 threads = 4 waves, tile of 64 pixels; wave w owns pixels [16w,16w+16).
// M = pixels, N = channels  =>  C/D layout gives each lane 4 CONSECUTIVE PIXELS of one
// channel => f32x4 nontemporal stores, perfectly suited to out[ch][pixel].
// Fragment layouts (HW-verified in round 2):
//   A[m=lane&15][k=quad*8+j]   B[k=quad*8+j][n=lane&15]   C/D: col=lane&15, row=quad*4+reg
__global__ __launch_bounds__(256) void pointnet_mfma(
    const float* __restrict__ x, const float* __restrict__ valid,
    const float* __restrict__ ws, float* __restrict__ out)
{
    __shared__ short h1[64 * 72];   // 9216 B, [pixel][ch] pad 72
    __shared__ short h2[64 * 72];   // 9216 B
    __shared__ float vld[64];

    const int t = threadIdx.x;
    const int pbase = blockIdx.x * 64;

    const float* __restrict__ A1 = ws + WS_A1;
    const float* __restrict__ C1 = ws + WS_C1;
    const float* __restrict__ C2 = ws + WS_C2;
    const float* __restrict__ C3 = ws + WS_C3;
    const short* __restrict__ W2f = (const short*)(ws + WS_BF);
    const short* __restrict__ W3f = W2f + 64 * 64;

    // ---- Layer 1: 3 -> 64 fp32, four threads per pixel (16 ch each) ----
    {
        const int pl = t & 63;
        const int half = t >> 6;       // == wave id, wave-uniform
        const int pg = pbase + pl;
        const float x0 = x[pg];
        const float x1 = x[pg + NPK];
        const float x2 = x[pg + 2 * NPK];
        if (half == 0) vld[pl] = valid[pg];
        const int cb = half * 16;
#pragma unroll
        for (int g = 0; g < 2; ++g) {
            bf16x8 vb;
#pragma unroll
            for (int j = 0; j < 8; ++j) {
                const int ch = cb + g * 8 + j;
                float a = C1[ch];
                a = fmaf(A1[ch * 3 + 0], x0, a);
                a = fmaf(A1[ch * 3 + 1], x1, a);
                a = fmaf(A1[ch * 3 + 2], x2, a);
                vb[j] = f2bf(fmaxf(a, 0.0f));
            }
            *(bf16x8*)&h1[pl * 72 + cb + g * 8] = vb;
        }
    }
    __syncthreads();

    const int lane = t & 63;
    const int w = t >> 6;
    const int lanelo = lane & 15;
    const int quad = lane >> 4;

    // ---- Layer 2: pixels(16) x 64ch_out, K=64 ----
    {
        bf16x8 a0 = *(const bf16x8*)&h1[(w * 16 + lanelo) * 72 + 0  + quad * 8];
        bf16x8 a1 = *(const bf16x8*)&h1[(w * 16 + lanelo) * 72 + 32 + quad * 8];
#pragma unroll
        for (int nt = 0; nt < 4; ++nt) {
            bf16x8 b0 = *(const bf16x8*)&W2f[((nt * 2 + 0) * 64 + lane) * 8];
            bf16x8 b1 = *(const bf16x8*)&W2f[((nt * 2 + 1) * 64 + lane) * 8];
            f32x4 acc = {0.f, 0.f, 0.f, 0.f};
            acc = __builtin_amdgcn_mfma_f32_16x16x32_bf16(a0, b0, acc, 0, 0, 0);
            acc = __builtin_amdgcn_mfma_f32_16x16x32_bf16(a1, b1, acc, 0, 0, 0);
            const float bias = C2[nt * 16 + lanelo];
#pragma unroll
            for (int r = 0; r < 4; ++r)
                h2[(w * 16 + quad * 4 + r) * 72 + nt * 16 + lanelo] =
                    f2bf(fmaxf(acc[r] + bias, 0.0f));
        }
    }
    __syncthreads();

    // ---- Layer 3: pixels(16) x 128ch_out, K=64; fused epilogue ----
    {
        bf16x8 a0 = *(const bf16x8*)&h2[(w * 16 + lanelo) * 72 + 0  + quad * 8];
        bf16x8 a1 = *(const bf16x8*)&h2[(w * 16 + lanelo) * 72 + 32 + quad * 8];
        const f32x4 v4 = *(const f32x4*)&vld[w * 16 + quad * 4];
        const int pstore = pbase + w * 16 + quad * 4;
#pragma unroll
        for (int nt = 0; nt < 8; ++nt) {
            bf16x8 b0 = *(const bf16x8*)&W3f[((nt * 2 + 0) * 64 + lane) * 8];
            bf16x8 b1 = *(const bf16x8*)&W3f[((nt * 2 + 1) * 64 + lane) * 8];
            f32x4 acc = {0.f, 0.f, 0.f, 0.f};
            acc = __builtin_amdgcn_mfma_f32_16x16x32_bf16(a0, b0, acc, 0, 0, 0);
            acc = __builtin_amdgcn_mfma_f32_16x16x32_bf16(a1, b1, acc, 0, 0, 0);
            const float bias = C3[nt * 16 + lanelo];
            f32x4 o;
#pragma unroll
            for (int r = 0; r < 4; ++r)
                o[r] = fmaxf(acc[r] + bias, 0.0f) * v4[r];
            __builtin_nontemporal_store(o, (f32x4*)&out[(nt * 16 + lanelo) * NPK + pstore]);
        }
    }
}

extern "C" void kernel_launch(void* const* d_in, const int* in_sizes, int n_in,
                              void* d_out, int out_size, void* d_ws, size_t ws_size,
                              hipStream_t stream) {
    const float* x     = (const float*)d_in[0];
    const float* valid = (const float*)d_in[1];

    const float* W1 = (const float*)d_in[2];
    const float* b1 = (const float*)d_in[3];
    const float* g1 = (const float*)d_in[4];
    const float* be1 = (const float*)d_in[5];
    const float* m1 = (const float*)d_in[6];
    const float* v1 = (const float*)d_in[7];

    const float* W2 = (const float*)d_in[8];
    const float* b2 = (const float*)d_in[9];
    const float* g2 = (const float*)d_in[10];
    const float* be2 = (const float*)d_in[11];
    const float* m2 = (const float*)d_in[12];
    const float* v2 = (const float*)d_in[13];

    const float* W3 = (const float*)d_in[14];
    const float* b3 = (const float*)d_in[15];
    const float* g3 = (const float*)d_in[16];
    const float* be3 = (const float*)d_in[17];
    const float* m3 = (const float*)d_in[18];
    const float* v3 = (const float*)d_in[19];

    float* ws  = (float*)d_ws;
    float* out = (float*)d_out;

    prep_kernel<<<1, 256, 0, stream>>>(W1, b1, g1, be1, m1, v1,
                                       W2, b2, g2, be2, m2, v2,
                                       W3, b3, g3, be3, m3, v3, ws);

    pointnet_mfma<<<NPK / 64, 256, 0, stream>>>(x, valid, ws, out);
}

// Round 4
// 340.942 us; speedup vs baseline: 1.1432x; 1.1432x over previous
//
#include <hip/hip_runtime.h>
#include <math.h>

#define EPS 1e-5f
#define NPK (4096 * 128)   // 524288 pixels

typedef __attribute__((ext_vector_type(8))) short bf16x8;   // 8 bf16 = 4 VGPRs
typedef __attribute__((ext_vector_type(4))) float f32x4;

__device__ __forceinline__ short f2bf(float f) {
    union { float f; unsigned u; } x; x.f = f;
    unsigned r = x.u + 0x7fffu + ((x.u >> 16) & 1u);   // round-to-nearest-even
    return (short)(r >> 16);
}

// ws layout (floats): A1[192] C1[64] C2[64] C3[128] | bf16: W2frag[4096] W3frag[8192]
// WNfrag = BN-folded weights pre-swizzled into MFMA B-fragment per-lane order:
//   frag[((nt*2+ks)*64 + lane)*8 + j] = Wfold[o = nt*16 + (lane&15)][i = ks*32 + (lane>>4)*8 + j]
#define WS_A1 0
#define WS_C1 192
#define WS_C2 256
#define WS_C3 320
#define WS_BF 448

__global__ void prep_kernel(
    const float* __restrict__ W1, const float* __restrict__ b1,
    const float* __restrict__ g1, const float* __restrict__ be1,
    const float* __restrict__ m1, const float* __restrict__ v1,
    const float* __restrict__ W2, const float* __restrict__ b2,
    const float* __restrict__ g2, const float* __restrict__ be2,
    const float* __restrict__ m2, const float* __restrict__ v2,
    const float* __restrict__ W3, const float* __restrict__ b3,
    const float* __restrict__ g3, const float* __restrict__ be3,
    const float* __restrict__ m3, const float* __restrict__ v3,
    float* __restrict__ ws)
{
    const int t = blockIdx.x * 256 + threadIdx.x;
    const int stride = gridDim.x * 256;
    if (t < 64) {
        float inv1 = g1[t] * rsqrtf(v1[t] + EPS);
        ws[WS_C1 + t] = b1[t] * inv1 + be1[t] - m1[t] * inv1;
        ws[WS_A1 + t * 3 + 0] = W1[t * 3 + 0] * inv1;
        ws[WS_A1 + t * 3 + 1] = W1[t * 3 + 1] * inv1;
        ws[WS_A1 + t * 3 + 2] = W1[t * 3 + 2] * inv1;
        float inv2 = g2[t] * rsqrtf(v2[t] + EPS);
        ws[WS_C2 + t] = b2[t] * inv2 + be2[t] - m2[t] * inv2;
    }
    if (t >= 128 && t < 256) {
        int o = t - 128;
        float inv3 = g3[o] * rsqrtf(v3[o] + EPS);
        ws[WS_C3 + o] = b3[o] * inv3 + be3[o] - m3[o] * inv3;
    }
    short* W2f = (short*)(ws + WS_BF);
    short* W3f = W2f + 64 * 64;
    for (int idx = t; idx < 64 * 64; idx += stride) {
        int j = idx & 7, lane = (idx >> 3) & 63, tile = idx >> 9;
        int nt = tile >> 1, ks = tile & 1;
        int o = nt * 16 + (lane & 15);
        int i = ks * 32 + (lane >> 4) * 8 + j;
        float inv = g2[o] * rsqrtf(v2[o] + EPS);
        W2f[idx] = f2bf(W2[o * 64 + i] * inv);
    }
    for (int idx = t; idx < 128 * 64; idx += stride) {
        int j = idx & 7, lane = (idx >> 3) & 63, tile = idx >> 9;
        int nt = tile >> 1, ks = tile & 1;
        int o = nt * 16 + (lane & 15);
        int i = ks * 32 + (lane >> 4) * 8 + j;
        float inv = g3[o] * rsqrtf(v3[o] + EPS);
        W3f[idx] = f2bf(W3[o * 64 + i] * inv);
    }
}

// One block = 256 threads = 4 waves, tile of 128 pixels; wave w owns pixels
// [32w, 32w+32) as TWO m-tiles of 16. M = pixels, N = channels => C/D layout
// gives each lane 4 CONSECUTIVE PIXELS of one channel => plain f32x4 stores
// (NO nontemporal: 64 B lane-segments must merge to full lines in L2 —
// NT bypass cost ~+31 us in round 3).
// Fragment layouts (HW-verified): A[m=lane&15][k=quad*8+j]
//   B[k=quad*8+j][n=lane&15]   C/D: col=lane&15, row=quad*4+reg
__global__ __launch_bounds__(256) void pointnet_mfma(
    const float* __restrict__ x, const float* __restrict__ valid,
    const float* __restrict__ ws, float* __restrict__ out)
{
    __shared__ short h1[128 * 72];   // 18432 B, [pixel][ch] pad 72
    __shared__ short h2[128 * 72];   // 18432 B
    __shared__ float vld[128];

    const int t = threadIdx.x;
    const int pbase = blockIdx.x * 128;

    const float* __restrict__ A1 = ws + WS_A1;
    const float* __restrict__ C1 = ws + WS_C1;
    const float* __restrict__ C2 = ws + WS_C2;
    const float* __restrict__ C3 = ws + WS_C3;
    const short* __restrict__ W2f = (const short*)(ws + WS_BF);
    const short* __restrict__ W3f = W2f + 64 * 64;

    // ---- Layer 1: 3 -> 64 fp32, two threads per pixel (32 ch each) ----
    {
        const int pl = t & 127;
        const int half = t >> 7;       // wave-uniform
        const int pg = pbase + pl;
        const float x0 = x[pg];
        const float x1 = x[pg + NPK];
        const float x2 = x[pg + 2 * NPK];
        if (half == 0) vld[pl] = valid[pg];
        const int cb = half * 32;
#pragma unroll
        for (int g = 0; g < 4; ++g) {
            bf16x8 vb;
#pragma unroll
            for (int j = 0; j < 8; ++j) {
                const int ch = cb + g * 8 + j;
                float a = C1[ch];
                a = fmaf(A1[ch * 3 + 0], x0, a);
                a = fmaf(A1[ch * 3 + 1], x1, a);
                a = fmaf(A1[ch * 3 + 2], x2, a);
                vb[j] = f2bf(fmaxf(a, 0.0f));
            }
            *(bf16x8*)&h1[pl * 72 + cb + g * 8] = vb;
        }
    }
    __syncthreads();

    const int lane = t & 63;
    const int w = t >> 6;
    const int lanelo = lane & 15;
    const int quad = lane >> 4;

    // ---- Layer 2: 2 m-tiles x 4 n-tiles, K=64 ----
    {
        bf16x8 a[2][2];
#pragma unroll
        for (int mt = 0; mt < 2; ++mt)
#pragma unroll
            for (int ks = 0; ks < 2; ++ks)
                a[mt][ks] = *(const bf16x8*)&h1[(w * 32 + mt * 16 + lanelo) * 72 + ks * 32 + quad * 8];
#pragma unroll
        for (int nt = 0; nt < 4; ++nt) {
            bf16x8 b0 = *(const bf16x8*)&W2f[((nt * 2 + 0) * 64 + lane) * 8];
            bf16x8 b1 = *(const bf16x8*)&W2f[((nt * 2 + 1) * 64 + lane) * 8];
            const float bias = C2[nt * 16 + lanelo];
#pragma unroll
            for (int mt = 0; mt < 2; ++mt) {
                f32x4 acc = {0.f, 0.f, 0.f, 0.f};
                acc = __builtin_amdgcn_mfma_f32_16x16x32_bf16(a[mt][0], b0, acc, 0, 0, 0);
                acc = __builtin_amdgcn_mfma_f32_16x16x32_bf16(a[mt][1], b1, acc, 0, 0, 0);
#pragma unroll
                for (int r = 0; r < 4; ++r)
                    h2[(w * 32 + mt * 16 + quad * 4 + r) * 72 + nt * 16 + lanelo] =
                        f2bf(fmaxf(acc[r] + bias, 0.0f));
            }
        }
    }
    __syncthreads();

    // ---- Layer 3: 2 m-tiles x 8 n-tiles, K=64; fused epilogue ----
    {
        bf16x8 a[2][2];
#pragma unroll
        for (int mt = 0; mt < 2; ++mt)
#pragma unroll
            for (int ks = 0; ks < 2; ++ks)
                a[mt][ks] = *(const bf16x8*)&h2[(w * 32 + mt * 16 + lanelo) * 72 + ks * 32 + quad * 8];
        f32x4 v4[2];
        v4[0] = *(const f32x4*)&vld[w * 32 + quad * 4];
        v4[1] = *(const f32x4*)&vld[w * 32 + 16 + quad * 4];
#pragma unroll
        for (int nt = 0; nt < 8; ++nt) {
            bf16x8 b0 = *(const bf16x8*)&W3f[((nt * 2 + 0) * 64 + lane) * 8];
            bf16x8 b1 = *(const bf16x8*)&W3f[((nt * 2 + 1) * 64 + lane) * 8];
            const float bias = C3[nt * 16 + lanelo];
            const long chbase = (long)(nt * 16 + lanelo) * NPK;
#pragma unroll
            for (int mt = 0; mt < 2; ++mt) {
                f32x4 acc = {0.f, 0.f, 0.f, 0.f};
                acc = __builtin_amdgcn_mfma_f32_16x16x32_bf16(a[mt][0], b0, acc, 0, 0, 0);
                acc = __builtin_amdgcn_mfma_f32_16x16x32_bf16(a[mt][1], b1, acc, 0, 0, 0);
                f32x4 o;
#pragma unroll
                for (int r = 0; r < 4; ++r)
                    o[r] = fmaxf(acc[r] + bias, 0.0f) * v4[mt][r];
                *(f32x4*)&out[chbase + pbase + w * 32 + mt * 16 + quad * 4] = o;
            }
        }
    }
}

extern "C" void kernel_launch(void* const* d_in, const int* in_sizes, int n_in,
                              void* d_out, int out_size, void* d_ws, size_t ws_size,
                              hipStream_t stream) {
    const float* x     = (const float*)d_in[0];
    const float* valid = (const float*)d_in[1];

    const float* W1 = (const float*)d_in[2];
    const float* b1 = (const float*)d_in[3];
    const float* g1 = (const float*)d_in[4];
    const float* be1 = (const float*)d_in[5];
    const float* m1 = (const float*)d_in[6];
    const float* v1 = (const float*)d_in[7];

    const float* W2 = (const float*)d_in[8];
    const float* b2 = (const float*)d_in[9];
    const float* g2 = (const float*)d_in[10];
    const float* be2 = (const float*)d_in[11];
    const float* m2 = (const float*)d_in[12];
    const float* v2 = (const float*)d_in[13];

    const float* W3 = (const float*)d_in[14];
    const float* b3 = (const float*)d_in[15];
    const float* g3 = (const float*)d_in[16];
    const float* be3 = (const float*)d_in[17];
    const float* m3 = (const float*)d_in[18];
    const float* v3 = (const float*)d_in[19];

    float* ws  = (float*)d_ws;
    float* out = (float*)d_out;

    prep_kernel<<<16, 256, 0, stream>>>(W1, b1, g1, be1, m1, v1,
                                        W2, b2, g2, be2, m2, v2,
                                        W3, b3, g3, be3, m3, v3, ws);

    pointnet_mfma<<<NPK / 128, 256, 0, stream>>>(x, valid, ws, out);
}